// Round 13
// baseline (334.452 us; speedup 1.0000x reference)
//
#include <hip/hip_runtime.h>
#include <hip/hip_bf16.h>

// ---------------- problem constants ----------------
#define S_LEN 4096
#define IN_DIM 768
#define D_DIM 512
#define N_HEADS 8
#define H_DIM 64
#define TSE_DIM 1536   // 3*DIM
#define NBLK 512       // persistent grid: 2 blocks/CU, co-resident by construction

typedef __attribute__((ext_vector_type(8))) short frag8;   // 8 bf16 = 4 VGPRs
typedef __attribute__((ext_vector_type(4))) float f32x4;

__device__ __forceinline__ unsigned short f2bfbits(float f) {
    unsigned int u = __float_as_uint(f);
    unsigned int r = (u + 0x7FFFu + ((u >> 16) & 1u)) >> 16;
    return (unsigned short)r;
}
__device__ __forceinline__ float bf2f(unsigned short b) {
    return __uint_as_float(((unsigned int)b) << 16);
}

// async global->LDS, 16B per lane. LDS dest wave-uniform; HW adds lane*16.
__device__ __forceinline__ void gload_lds16(const void* g, void* l) {
    __builtin_amdgcn_global_load_lds(
        (const __attribute__((address_space(1))) unsigned int*)g,
        (__attribute__((address_space(3))) unsigned int*)l,
        16, 0, 0);
}

// ---- generation-counter global barrier (all NBLK blocks co-resident) ----
// Release: __syncthreads drains every wave's stores (vmcnt0) to L2, then thread 0's
// __threadfence publishes L2 device-wide. Acquire: spin on device-scope atomic load,
// then fence invalidates stale L1/L2 (G16 cross-XCD discipline).
__device__ __forceinline__ void gbar(unsigned* bar, unsigned* gen) {
    __syncthreads();
    if (threadIdx.x == 0) {
        const unsigned want = ++(*gen);
        __threadfence();
        unsigned arrived = __hip_atomic_fetch_add(bar, 1u, __ATOMIC_ACQ_REL,
                                                  __HIP_MEMORY_SCOPE_AGENT) + 1u;
        if (arrived == NBLK) {
            __hip_atomic_store(bar, 0u, __ATOMIC_RELAXED, __HIP_MEMORY_SCOPE_AGENT);
            __hip_atomic_store(bar + 1, want, __ATOMIC_RELEASE, __HIP_MEMORY_SCOPE_AGENT);
        } else {
            while (__hip_atomic_load(bar + 1, __ATOMIC_ACQUIRE,
                                     __HIP_MEMORY_SCOPE_AGENT) != want)
                __builtin_amdgcn_s_sleep(4);
        }
        __threadfence();
    }
    __syncthreads();
}

// ---------------- R5 64x64 GEMM tile as a device function ----------------
// C[.][N] = A[.][K] * Bt[N][K]^T (+bias). 4 waves (2x2), 2-phase dbuf, gload_lds w16.
template<int K, bool OUT_BF16, bool BIAS>
__device__ __forceinline__ void gemm_tile(
        const unsigned short* __restrict__ A,
        const unsigned short* __restrict__ Bt,
        const float* __restrict__ bias, void* __restrict__ C,
        int N, int bm, int bn,
        unsigned short (*__restrict__ As)[64 * 32],
        unsigned short (*__restrict__ Bs)[64 * 32]) {
    constexpr int NT = K >> 5;
    const int lane = threadIdx.x & 63;
    const int wave = threadIdx.x >> 6;
    const int wr = wave >> 1, wc = wave & 1;
    const int fr = lane & 15, fg = lane >> 4;
    const int srow = lane >> 2, scol = (lane & 3) * 8;

    const unsigned short* agp = A  + (size_t)(bm + wave * 16 + srow) * K + scol;
    const unsigned short* bgp = Bt + (size_t)(bn + wave * 16 + srow) * K + scol;

    f32x4 acc[2][2];
    #pragma unroll
    for (int mi = 0; mi < 2; ++mi)
        #pragma unroll
        for (int ni = 0; ni < 2; ++ni)
            acc[mi][ni] = (f32x4)(0.f);

    __syncthreads();                 // protect LDS reuse from the previous tile
    gload_lds16(agp, &As[0][wave * 512]);
    gload_lds16(bgp, &Bs[0][wave * 512]);
    __syncthreads();

    int cur = 0;
    #pragma unroll
    for (int kt = 0; kt + 1 < NT; ++kt) {
        const int ko = (kt + 1) << 5;
        gload_lds16(agp + ko, &As[cur ^ 1][wave * 512]);
        gload_lds16(bgp + ko, &Bs[cur ^ 1][wave * 512]);

        frag8 a[2], b[2];
        #pragma unroll
        for (int mi = 0; mi < 2; ++mi)
            a[mi] = *(const frag8*)&As[cur][(wr * 32 + mi * 16 + fr) * 32 + fg * 8];
        #pragma unroll
        for (int ni = 0; ni < 2; ++ni)
            b[ni] = *(const frag8*)&Bs[cur][(wc * 32 + ni * 16 + fr) * 32 + fg * 8];
        #pragma unroll
        for (int mi = 0; mi < 2; ++mi)
            #pragma unroll
            for (int ni = 0; ni < 2; ++ni)
                acc[mi][ni] = __builtin_amdgcn_mfma_f32_16x16x32_bf16(
                        a[mi], b[ni], acc[mi][ni], 0, 0, 0);

        __syncthreads();
        cur ^= 1;
    }

    {   // epilogue tile (no prefetch)
        frag8 a[2], b[2];
        #pragma unroll
        for (int mi = 0; mi < 2; ++mi)
            a[mi] = *(const frag8*)&As[cur][(wr * 32 + mi * 16 + fr) * 32 + fg * 8];
        #pragma unroll
        for (int ni = 0; ni < 2; ++ni)
            b[ni] = *(const frag8*)&Bs[cur][(wc * 32 + ni * 16 + fr) * 32 + fg * 8];
        #pragma unroll
        for (int mi = 0; mi < 2; ++mi)
            #pragma unroll
            for (int ni = 0; ni < 2; ++ni)
                acc[mi][ni] = __builtin_amdgcn_mfma_f32_16x16x32_bf16(
                        a[mi], b[ni], acc[mi][ni], 0, 0, 0);
    }

    // C/D layout col=lane&15, row=(lane>>4)*4+reg  [HW-verified m89/m91]
    #pragma unroll
    for (int mi = 0; mi < 2; ++mi) {
        int grow = bm + wr * 32 + mi * 16 + fg * 4;
        #pragma unroll
        for (int ni = 0; ni < 2; ++ni) {
            int gcol = bn + wc * 32 + ni * 16 + fr;
            float bv = BIAS ? bias[gcol] : 0.f;
            #pragma unroll
            for (int r = 0; r < 4; ++r) {
                float v = acc[mi][ni][r] + bv;
                if (OUT_BF16)
                    ((unsigned short*)C)[(size_t)(grow + r) * N + gcol] = f2bfbits(v);
                else
                    ((float*)C)[(size_t)(grow + r) * N + gcol] = v;
            }
        }
    }
}

// ---------------- the persistent mega-kernel: 5 phases, 4 global barriers ----------
__global__ __launch_bounds__(256, 2) void mega_kernel(
        const float4* __restrict__ x4,
        const float* __restrict__ W_in,  const float* __restrict__ b_in,
        const float* __restrict__ W_tse,
        const float* __restrict__ W_out, const float* __restrict__ b_out,
        unsigned short* __restrict__ xb,
        unsigned short* __restrict__ WinT,
        unsigned short* __restrict__ WtseT,
        unsigned short* __restrict__ WoutT,
        unsigned short* __restrict__ h,
        unsigned short* __restrict__ tse,
        unsigned short* __restrict__ attnb,
        float* __restrict__ out,
        unsigned* __restrict__ bar) {
    __shared__ float tile[32][33];
    __shared__ __align__(16) unsigned short As[2][64 * 32];
    __shared__ __align__(16) unsigned short Bs[2][64 * 32];

    const int bid  = blockIdx.x;
    const int lane = threadIdx.x & 63;
    const int wave = threadIdx.x >> 6;
    unsigned gen = 0;

    // ---- phase 0: prep (x->bf16 + 3 weight transpose-converts), 4480 units ----
    for (int b = bid; b < 4480; b += NBLK) {
        if (b < 3072) {
            int i = b * 256 + threadIdx.x;
            float4 v = x4[i];
            ushort4 o;
            o.x = f2bfbits(v.x); o.y = f2bfbits(v.y);
            o.z = f2bfbits(v.z); o.w = f2bfbits(v.w);
            ((ushort4*)xb)[i] = o;
        } else {
            const float* in; unsigned short* outw; int K, N, t;
            if (b < 3456)      { t = b - 3072; in = W_in;  outw = WinT;  K = IN_DIM; N = D_DIM;  }
            else if (b < 4224) { t = b - 3456; in = W_tse; outw = WtseT; K = D_DIM;  N = TSE_DIM;}
            else               { t = b - 4224; in = W_out; outw = WoutT; K = D_DIM;  N = D_DIM;  }
            int ktiles = K / 32;
            int kb = (t % ktiles) * 32, nb = (t / ktiles) * 32;
            int tx = threadIdx.x & 31, ty = threadIdx.x >> 5;
            #pragma unroll
            for (int r = ty; r < 32; r += 8)
                tile[r][tx] = in[(size_t)(kb + r) * N + nb + tx];
            __syncthreads();
            #pragma unroll
            for (int r = ty; r < 32; r += 8)
                outw[(size_t)(nb + r) * K + kb + tx] = f2bfbits(tile[tx][r]);
            __syncthreads();   // protect tile reuse by the next unit
        }
    }
    gbar(bar, &gen);

    // ---- phase 1: h = x @ W_in + b_in (bf16), 512 tiles ----
    for (int t = bid; t < 512; t += NBLK)
        gemm_tile<IN_DIM, true, true>(xb, WinT, b_in, h, D_DIM,
                                      (t & 63) * 64, (t >> 6) * 64, As, Bs);
    gbar(bar, &gen);

    // ---- phase 2: tse = h @ W_tse (bf16), 1536 tiles ----
    for (int t = bid; t < 1536; t += NBLK)
        gemm_tile<D_DIM, true, false>(h, WtseT, nullptr, tse, TSE_DIM,
                                      (t & 63) * 64, (t >> 6) * 64, As, Bs);
    gbar(bar, &gen);

    // ---- phase 3: dilated attention, 1024 units of 4 rows ----
    for (int u = bid; u < 1024; u += NBLK) {
        const int s   = u * 4 + wave;
        const int off = (lane >> 3) * H_DIM + (lane & 7) * 8;   // h*64 + d8*8

        float qf[8];
        {
            frag8 q = *(const frag8*)(tse + (size_t)s * TSE_DIM + off);
            #pragma unroll
            for (int i = 0; i < 8; ++i) qf[i] = bf2f((unsigned short)q[i]);
        }

        float sc[7];
        #pragma unroll
        for (int j = 0; j < 7; ++j) {
            int t = s + (j - 3) * 8;
            bool valid = (t >= 0) && (t < S_LEN);
            float p = 0.f;
            if (valid) {
                frag8 k = *(const frag8*)(tse + (size_t)t * TSE_DIM + D_DIM + off);
                #pragma unroll
                for (int i = 0; i < 8; ++i) p += qf[i] * bf2f((unsigned short)k[i]);
            }
            p += __shfl_xor(p, 1, 64);
            p += __shfl_xor(p, 2, 64);
            p += __shfl_xor(p, 4, 64);
            sc[j] = valid ? p * 0.125f : -__builtin_inff();
        }

        float m = sc[0];
        #pragma unroll
        for (int j = 1; j < 7; ++j) m = fmaxf(m, sc[j]);

        float w[7], denom = 0.f;
        #pragma unroll
        for (int j = 0; j < 7; ++j) {
            w[j] = (sc[j] == -__builtin_inff()) ? 0.f : __expf(sc[j] - m);
            denom += w[j];
        }
        const float inv = 1.f / denom;

        float of[8];
        #pragma unroll
        for (int i = 0; i < 8; ++i) of[i] = 0.f;
        #pragma unroll
        for (int j = 0; j < 7; ++j) {
            int t = s + (j - 3) * 8;
            if (t >= 0 && t < S_LEN) {
                frag8 v = *(const frag8*)(tse + (size_t)t * TSE_DIM + 2 * D_DIM + off);
                #pragma unroll
                for (int i = 0; i < 8; ++i) of[i] += w[j] * bf2f((unsigned short)v[i]);
            }
        }

        frag8 o;
        #pragma unroll
        for (int i = 0; i < 8; ++i) o[i] = (short)f2bfbits(of[i] * inv);
        *(frag8*)(attnb + (size_t)s * D_DIM + off) = o;
    }
    gbar(bar, &gen);

    // ---- phase 4: out = attn @ W_out + b_out (fp32), 512 tiles ----
    for (int t = bid; t < 512; t += NBLK)
        gemm_tile<D_DIM, false, true>(attnb, WoutT, b_out, out, D_DIM,
                                      (t & 63) * 64, (t >> 6) * 64, As, Bs);
}

// ---------------- launch ----------------
extern "C" void kernel_launch(void* const* d_in, const int* in_sizes, int n_in,
                              void* d_out, int out_size, void* d_ws, size_t ws_size,
                              hipStream_t stream) {
    (void)in_sizes; (void)n_in; (void)out_size;
    const float* x     = (const float*)d_in[0];
    const float* W_in  = (const float*)d_in[1];
    const float* b_in  = (const float*)d_in[2];
    const float* W_tse = (const float*)d_in[3];
    const float* W_out = (const float*)d_in[4];
    const float* b_out = (const float*)d_in[5];

    char* p = (char*)d_ws;
    unsigned short* xb    = (unsigned short*)p; p += (size_t)S_LEN * IN_DIM * 2;
    unsigned short* WinT  = (unsigned short*)p; p += (size_t)D_DIM * IN_DIM * 2;
    unsigned short* WtseT = (unsigned short*)p; p += (size_t)TSE_DIM * D_DIM * 2;
    unsigned short* WoutT = (unsigned short*)p; p += (size_t)D_DIM * D_DIM * 2;
    unsigned short* h     = (unsigned short*)p; p += (size_t)S_LEN * D_DIM * 2;
    unsigned short* tse   = (unsigned short*)p; p += (size_t)S_LEN * TSE_DIM * 2;
    unsigned short* attnb = (unsigned short*)p; p += (size_t)S_LEN * D_DIM * 2;
    unsigned*       bar   = (unsigned*)p;       p += 2 * sizeof(unsigned);
    if ((size_t)(p - (char*)d_ws) > ws_size) return;

    // zero the barrier state each call (poison-safe, replay-deterministic)
    hipMemsetAsync(bar, 0, 2 * sizeof(unsigned), stream);

    mega_kernel<<<NBLK, 256, 0, stream>>>(
            (const float4*)x, W_in, b_in, W_tse, W_out, b_out,
            xb, WinT, WtseT, WoutT, h, tse, attnb, (float*)d_out, bar);
}